// Round 20
// baseline (52.700 us; speedup 1.0000x reference)
//
#include <hip/hip_runtime.h>

#define Oo    32
#define F2    4096
#define GRID  256            // (oq:4) x (h:64) -> 1 block/CU
#define SLOTS 64             // per-o partial slots: one per h-row block
#define NTOT  (32 * F2)

typedef _Float16 h2 __attribute__((ext_vector_type(2)));
typedef _Float16 h8 __attribute__((ext_vector_type(8)));

#if __has_builtin(__builtin_amdgcn_fdot2)
#define DOT2(a, b, c) __builtin_amdgcn_fdot2((a), (b), (c), false)
#else
__device__ __forceinline__ float DOT2(h2 a, h2 b, float c) {
    return c + (float)a.x * (float)b.x + (float)a.y * (float)b.y;
}
#endif

__device__ __forceinline__ unsigned pkh2f(float a, float b) {
    h2 t; t.x = (_Float16)a; t.y = (_Float16)b;
    return __builtin_bit_cast(unsigned, t);
}
__device__ __forceinline__ h2 bch2(unsigned u) { return __builtin_bit_cast(h2, u); }

// lgkm-only barrier (T4 adapted): this kernel's global loads land ONLY in
// private VGPRs (never LDS), so cross-wave visibility at barriers needs just
// lgkmcnt(0) (ds ops). __syncthreads() would emit s_waitcnt vmcnt(0) and
// DRAIN the chunk-ahead prefetch at every barrier — r16/r19's loads never
// overlapped compute (the ~16us gap over the 8us HBM floor). With this
// barrier the ISSUE(cp+2) loads stay in flight across two barriers and the
// whole COMPUTE(cp+1); the compiler still inserts counted vmcnt before
// WRITEX/WRITEW consume the staged regs (data dependence).
__device__ __forceinline__ void bar_lgkm() {
    asm volatile("s_waitcnt lgkmcnt(0)\n\ts_barrier" ::: "memory");
}

// r16/r19 structure otherwise VERBATIM (full-row DRAM-contiguity tile;
// 2-dispatch tail with stats folded into apply — 30.4us, passed post-timing).
template <typename YT>
__global__ __launch_bounds__(512) void svconv_kernel(
    const float* __restrict__ x, const float* __restrict__ wgt,
    const float* __restrict__ bias, YT* __restrict__ y,
    float* __restrict__ psum, float* __restrict__ psumsq)
{
    __shared__ __align__(16) unsigned ldsX[3 * 32 * 68];     // [kh][b][w'] 26.1KB
    __shared__ __align__(16) unsigned ldsW[2 * 9 * 8 * 64];  // [buf][k][o][f] 36.9KB

    const int tid = threadIdx.x;
    const int f   = tid & 63;
    const int bq  = tid >> 6;                 // 0..7
    const int oq  = blockIdx.x >> 6;          // 0..3
    const int h   = blockIdx.x & 63;
    const int col = h * 64 + f;

    // ---- weight slots: tid<288 = (o:8)x(k:9)x(q:4); 16 floats x 2 p-rows ----
    const bool wOK = (tid < 288);
    int wg = 0, wl = 0;
    {
        int s = wOK ? tid : 0;
        int o_ = s / 36, rm = s - 36 * o_;
        int k_ = rm >> 2, q_ = rm & 3;
        wg = ((oq * 8 + o_) * 72 + k_) * F2 + h * 64 + 16 * q_;  // +cp*18*F2, pair +9*F2
        wl = (k_ * 8 + o_) * 64 + 16 * q_;
    }

    // ---- x slots: tid<384 = (kh:3)x(b:32)x(q:4); 16 floats x 2 channels ----
    bool xOK = false;
    int xg = 0, xl = 0;
    {
        int s = (tid < 384) ? tid : 0;
        int kh_ = s >> 7, b_ = (s >> 2) & 31, q_ = s & 3;
        int gh = h - 1 + kh_;
        xOK = (tid < 384) && ((unsigned)gh < 64u);
        xg = b_ * 32768 + gh * 64 + 16 * q_;          // + c*4096 at issue
        xl = (kh_ * 32 + b_) * 68 + 16 * q_;
    }

    // x tap indices (halo cols at w'=64 (left) and 65 (right), zero forever)
    const int wi0 = (f == 0)  ? 64 : f - 1;
    const int wi2 = (f == 63) ? 65 : f + 1;

    float bz[8];
#pragma unroll
    for (int j = 0; j < 8; ++j) bz[j] = bias[(oq * 8 + j) * F2 + col];

    float acc[8][4];
#pragma unroll
    for (int j = 0; j < 8; ++j)
#pragma unroll
        for (int i = 0; i < 4; ++i) acc[j][i] = 0.f;

    float4 xr0[4], xr1[4], wr0[4], wr1[4];    // staged regs (one chunk in flight)

    auto ISSUEX = [&](int cp) {
        if (xOK) {
            const int c0 = xg + cp * 8192;
#pragma unroll
            for (int e = 0; e < 4; ++e) {
                xr0[e] = *(const float4*)(x + c0 + 4 * e);
                xr1[e] = *(const float4*)(x + c0 + 4096 + 4 * e);
            }
        }
    };
    auto ISSUEW = [&](int cp) {
        if (wOK) {
            const int g0 = wg + cp * 18 * F2;
#pragma unroll
            for (int e = 0; e < 4; ++e) {
                wr0[e] = *(const float4*)(wgt + g0 + 4 * e);
                wr1[e] = *(const float4*)(wgt + g0 + 9 * F2 + 4 * e);
            }
        }
    };
    auto WRITEX = [&]() {
        if (xOK) {
#pragma unroll
            for (int e = 0; e < 4; ++e) {
                uint4 pk;
                pk.x = pkh2f(xr0[e].x, xr1[e].x);
                pk.y = pkh2f(xr0[e].y, xr1[e].y);
                pk.z = pkh2f(xr0[e].z, xr1[e].z);
                pk.w = pkh2f(xr0[e].w, xr1[e].w);
                *(uint4*)&ldsX[xl + 4 * e] = pk;
            }
        }
    };
    auto WRITEW = [&](int buf) {
        if (wOK) {
#pragma unroll
            for (int e = 0; e < 4; ++e) {
                uint4 pk;
                pk.x = pkh2f(wr0[e].x, wr1[e].x);
                pk.y = pkh2f(wr0[e].y, wr1[e].y);
                pk.z = pkh2f(wr0[e].z, wr1[e].z);
                pk.w = pkh2f(wr0[e].w, wr1[e].w);
                *(uint4*)&ldsW[buf * 4608 + wl + 4 * e] = pk;
            }
        }
    };
    auto COMPUTE = [&](int wbuf) {
        const unsigned* wb = &ldsW[wbuf * 4608];
#pragma unroll
        for (int k = 0; k < 9; ++k) {
            const int kh = k / 3, kw = k - 3 * kh;
            const int wi = (kw == 0) ? wi0 : ((kw == 1) ? f : wi2);
            h2 wv[8];
#pragma unroll
            for (int j = 0; j < 8; ++j) wv[j] = bch2(wb[k * 512 + j * 64 + f]);
#pragma unroll
            for (int i = 0; i < 4; ++i) {
                h2 xv = bch2(ldsX[(kh * 32 + bq * 4 + i) * 68 + wi]);
#pragma unroll
                for (int j = 0; j < 8; ++j)
                    acc[j][i] = DOT2(wv[j], xv, acc[j][i]);
            }
        }
    };

    // ---- prologue: zero x LDS (halos stay zero forever); chunk0 staged ----
    // Race audit for lgkm-only barriers: barriers order ONLY ds ops (reads of
    // a buffer complete before it is overwritten; writes visible before the
    // next COMPUTE). Global->VGPR loads are private: the compiler emits
    // counted vmcnt before WRITEX/WRITEW read the staged regs. Reg WAR:
    // ISSUE(k)'s regs are consumed by WRITE at phase k-1, before ISSUE(k+1).
    ISSUEX(0); ISSUEW(0);
    for (int i = tid; i < 3 * 32 * 68; i += 512) ldsX[i] = 0u;
    bar_lgkm();                            // zeros visible; ISSUE(0) in flight
    WRITEX(); WRITEW(0);
    ISSUEX(1); ISSUEW(1);
    bar_lgkm();                            // chunk0 visible; ISSUE(1) in flight

#pragma unroll
    for (int cp = 0; cp < 4; ++cp) {
        COMPUTE(cp & 1);
        if (cp < 3) {
            bar_lgkm();                    // all waves' x reads done
            WRITEX(); WRITEW((cp + 1) & 1);
            if (cp < 2) { ISSUEX(cp + 2); ISSUEW(cp + 2); }
            bar_lgkm();                    // writes visible; prefetch in flight
        }
    }
    __syncthreads();                       // free ldsX for scratch reuse

    // ---- epilogue: bias, y store, BN partials ----
    float s_[8], ss_[8];
#pragma unroll
    for (int j = 0; j < 8; ++j) {
        s_[j] = 0.f; ss_[j] = 0.f;
#pragma unroll
        for (int i = 0; i < 4; ++i) {
            float a = acc[j][i] + bz[j];
            y[(size_t)((bq * 4 + i) * Oo + oq * 8 + j) * F2 + col] = (YT)a;
            s_[j] += a; ss_[j] = fmaf(a, a, ss_[j]);
        }
    }
    if (psum != nullptr) {
#pragma unroll
        for (int j = 0; j < 8; ++j)
#pragma unroll
            for (int d = 32; d >= 1; d >>= 1) {
                s_[j]  += __shfl_down(s_[j],  d, 64);
                ss_[j] += __shfl_down(ss_[j], d, 64);
            }
        float* scr = (float*)ldsX;          // [2][bq:8][o:8]
        if (f == 0) {
#pragma unroll
            for (int j = 0; j < 8; ++j) {
                scr[bq * 8 + j]      = s_[j];
                scr[64 + bq * 8 + j] = ss_[j];
            }
        }
        __syncthreads();
        if (tid < 64) {
            int j = tid >> 3, g = tid & 7;  // g = bq
            float v  = scr[g * 8 + j];
            float vv = scr[64 + g * 8 + j];
#pragma unroll
            for (int d = 4; d >= 1; d >>= 1) {
                v  += __shfl_down(v,  d, 8);
                vv += __shfl_down(vv, d, 8);
            }
            if (g == 0) {
                psum[(oq * 8 + j) * SLOTS + h]   = v;
                psumsq[(oq * 8 + j) * SLOTS + h] = vv;
            }
        }
    }
}

// ---- fused stats+apply: each block serves one o; 64 lanes reduce psum ----
__global__ __launch_bounds__(256) void bnapply_fused_kernel(
    const _Float16* __restrict__ yh, const float* __restrict__ psum,
    const float* __restrict__ psumsq, const float* __restrict__ gamma,
    const float* __restrict__ beta, float* __restrict__ y)
{
    __shared__ float scsh[2];
    const int o = (blockIdx.x >> 1) & 31;      // constant per block
    const int t = threadIdx.x;
    if (t < 64) {
        float v  = psum[o * SLOTS + t];
        float vv = psumsq[o * SLOTS + t];
#pragma unroll
        for (int d = 32; d >= 1; d >>= 1) {
            v  += __shfl_down(v,  d, 64);
            vv += __shfl_down(vv, d, 64);
        }
        if (t == 0) {
            float mean = v / (float)NTOT;
            float var  = vv / (float)NTOT - mean * mean;
            float rstd = rsqrtf(var + 1e-5f);
            float scl  = gamma[o] * rstd;
            scsh[0] = scl;
            scsh[1] = beta[o] - mean * scl;
        }
    }
    __syncthreads();
    const float scl = scsh[0], sh = scsh[1];

    int i = blockIdx.x * 256 + t;              // 8-element packs; 524288 total
    h8 v = ((const h8*)yh)[i];
    float4 lo, hi;
    lo.x = fmaf((float)v[0], scl, sh);
    lo.y = fmaf((float)v[1], scl, sh);
    lo.z = fmaf((float)v[2], scl, sh);
    lo.w = fmaf((float)v[3], scl, sh);
    hi.x = fmaf((float)v[4], scl, sh);
    hi.y = fmaf((float)v[5], scl, sh);
    hi.z = fmaf((float)v[6], scl, sh);
    hi.w = fmaf((float)v[7], scl, sh);
    ((float4*)y)[2 * i]     = lo;
    ((float4*)y)[2 * i + 1] = hi;
}

// ======== fallback kernels (r16-proven) ========
__global__ __launch_bounds__(64) void bnstats_kernel(
    const float* __restrict__ psum, const float* __restrict__ psumsq,
    const float* __restrict__ gamma, const float* __restrict__ beta,
    float* __restrict__ scsh)
{
    const int o = blockIdx.x;
    const int t = threadIdx.x;
    float s  = psum[o * SLOTS + t];
    float ss = psumsq[o * SLOTS + t];
#pragma unroll
    for (int d = 32; d >= 1; d >>= 1) {
        s  += __shfl_down(s, d, 64);
        ss += __shfl_down(ss, d, 64);
    }
    if (t == 0) {
        float mean = s / (float)NTOT;
        float var  = ss / (float)NTOT - mean * mean;
        float rstd = rsqrtf(var + 1e-5f);
        float scl  = gamma[o] * rstd;
        scsh[o]      = scl;
        scsh[Oo + o] = beta[o] - mean * scl;
    }
}

__global__ __launch_bounds__(256) void bnapply_kernel(
    float* __restrict__ y, const float* __restrict__ scsh)
{
    int i = blockIdx.x * 256 + threadIdx.x;    // float4 index
    float4 v = ((const float4*)y)[i];
    int o = (i >> 10) & 31;
    float scl = scsh[o], sh = scsh[Oo + o];
    v.x = fmaf(v.x, scl, sh);
    v.y = fmaf(v.y, scl, sh);
    v.z = fmaf(v.z, scl, sh);
    v.w = fmaf(v.w, scl, sh);
    ((float4*)y)[i] = v;
}

__global__ __launch_bounds__(256) void bnreduce_y_kernel(
    const float* __restrict__ y, float* __restrict__ seg, float* __restrict__ segsq)
{
    const int o  = blockIdx.x >> 3;
    const int sg = blockIdx.x & 7;
    const int t  = threadIdx.x;
    float s = 0.f, ss = 0.f;
    for (int i = t; i < 4 * 1024; i += 256) {
        int b   = sg * 4 + (i >> 10);
        int fof = (i & 1023) * 4;
        float4 v = *(const float4*)(y + (size_t)(b * Oo + o) * F2 + fof);
        s  += (v.x + v.y) + (v.z + v.w);
        ss += v.x * v.x + v.y * v.y + v.z * v.z + v.w * v.w;
    }
#pragma unroll
    for (int d = 32; d >= 1; d >>= 1) {
        s  += __shfl_down(s, d, 64);
        ss += __shfl_down(ss, d, 64);
    }
    __shared__ float ls[4], lss[4];
    int wv = t >> 6, ln = t & 63;
    if (ln == 0) { ls[wv] = s; lss[wv] = ss; }
    __syncthreads();
    if (t == 0) {
        seg[blockIdx.x]   = (ls[0] + ls[1]) + (ls[2] + ls[3]);
        segsq[blockIdx.x] = (lss[0] + lss[1]) + (lss[2] + lss[3]);
    }
}

__global__ __launch_bounds__(256) void bnstats2_kernel(
    const float* __restrict__ seg, const float* __restrict__ segsq,
    const float* __restrict__ gamma, const float* __restrict__ beta,
    float* __restrict__ scsh)
{
    const int t = threadIdx.x;
    const int o = t >> 3, g = t & 7;
    float v  = seg[t];
    float vv = segsq[t];
#pragma unroll
    for (int d = 4; d >= 1; d >>= 1) {
        v  += __shfl_down(v,  d, 8);
        vv += __shfl_down(vv, d, 8);
    }
    if (g == 0) {
        float mean = v / (float)NTOT;
        float var  = vv / (float)NTOT - mean * mean;
        float rstd = rsqrtf(var + 1e-5f);
        float scl  = gamma[o] * rstd;
        scsh[o]      = scl;
        scsh[Oo + o] = beta[o] - mean * scl;
    }
}

extern "C" void kernel_launch(void* const* d_in, const int* in_sizes, int n_in,
                              void* d_out, int out_size, void* d_ws, size_t ws_size,
                              hipStream_t stream)
{
    const float* x     = (const float*)d_in[0];
    const float* wgt   = (const float*)d_in[1];
    const float* bias  = (const float*)d_in[2];
    const float* gamma = (const float*)d_in[3];
    const float* beta  = (const float*)d_in[4];
    float* y = (float*)d_out;

    const size_t n_elems    = (size_t)NTOT * Oo;              // 4,194,304
    const size_t yh_bytes   = n_elems * sizeof(_Float16);     // 8 MiB
    const size_t psum_bytes = (size_t)(2 * Oo * SLOTS + 2 * Oo) * sizeof(float);

    if (ws_size >= yh_bytes + psum_bytes) {
        // primary: f16 intermediate y in ws; 2 dispatches
        _Float16* yh  = (_Float16*)d_ws;
        float* psum   = (float*)((char*)d_ws + yh_bytes);     // [Oo][SLOTS]
        float* psumsq = psum + Oo * SLOTS;
        svconv_kernel<_Float16><<<GRID, 512, 0, stream>>>(x, wgt, bias, yh, psum, psumsq);
        bnapply_fused_kernel<<<(int)(n_elems / 8 / 256), 256, 0, stream>>>(
            yh, psum, psumsq, gamma, beta, y);
    } else if (ws_size >= psum_bytes) {
        // secondary: fp32 y in d_out, partials in ws
        float* psum   = (float*)d_ws;
        float* psumsq = psum + Oo * SLOTS;
        float* scsh   = psumsq + Oo * SLOTS;
        svconv_kernel<float><<<GRID, 512, 0, stream>>>(x, wgt, bias, y, psum, psumsq);
        bnstats_kernel<<<Oo, 64, 0, stream>>>(psum, psumsq, gamma, beta, scsh);
        bnapply_kernel<<<(int)(n_elems / 4 / 256), 256, 0, stream>>>(y, scsh);
    } else {
        // tertiary: tiny scratch — reduce y directly
        float* seg   = (float*)d_ws;                          // [256]
        float* segsq = seg + 256;
        float* scsh  = segsq + 256;
        svconv_kernel<float><<<GRID, 512, 0, stream>>>(x, wgt, bias, y, nullptr, nullptr);
        bnreduce_y_kernel<<<256, 256, 0, stream>>>(y, seg, segsq);
        bnstats2_kernel<<<1, 256, 0, stream>>>(seg, segsq, gamma, beta, scsh);
        bnapply_kernel<<<(int)(n_elems / 4 / 256), 256, 0, stream>>>(y, scsh);
    }
}

// Round 21
// 30.220 us; speedup vs baseline: 1.7438x; 1.7438x over previous
//
#include <hip/hip_runtime.h>

#define Oo    32
#define F2    4096
#define GRID  256            // (oq:4) x (h:64) -> 1 block/CU
#define SLOTS 64             // per-o partial slots: one per h-row block
#define NTOT  (32 * F2)

typedef _Float16 h2 __attribute__((ext_vector_type(2)));
typedef _Float16 h8 __attribute__((ext_vector_type(8)));

#if __has_builtin(__builtin_amdgcn_fdot2)
#define DOT2(a, b, c) __builtin_amdgcn_fdot2((a), (b), (c), false)
#else
__device__ __forceinline__ float DOT2(h2 a, h2 b, float c) {
    return c + (float)a.x * (float)b.x + (float)a.y * (float)b.y;
}
#endif

__device__ __forceinline__ unsigned pkh2f(float a, float b) {
    h2 t; t.x = (_Float16)a; t.y = (_Float16)b;
    return __builtin_bit_cast(unsigned, t);
}
__device__ __forceinline__ h2 bch2(unsigned u) { return __builtin_bit_cast(h2, u); }

// r19 kernel (30.4us, passed post-timing) with ONE scheduling change:
// ISSUE(cp+2) moved from BETWEEN the two barriers to AFTER the second
// barrier (just before COMPUTE(cp+1)). __syncthreads() drains vmcnt(0);
// in r19 that drain came right after issuing the prefetch -> full HBM
// latency+BW exposed serially at every barrier. Now every vmcnt-draining
// barrier is a full COMPUTE phase (~5000cy ~ per-chunk load time) after the
// loads were issued -> overlap without asm barriers. (r20's lgkm-only asm
// barrier is reverted: its memory clobber broke regalloc -> VGPR 128 +
// 76MB scratch spill.) Register lifetimes identical to r19 (ISSUE regs
// live across exactly one COMPUTE either way) -> no new pressure.
template <typename YT>
__global__ __launch_bounds__(512) void svconv_kernel(
    const float* __restrict__ x, const float* __restrict__ wgt,
    const float* __restrict__ bias, YT* __restrict__ y,
    float* __restrict__ psum, float* __restrict__ psumsq)
{
    __shared__ __align__(16) unsigned ldsX[3 * 32 * 68];     // [kh][b][w'] 26.1KB
    __shared__ __align__(16) unsigned ldsW[2 * 9 * 8 * 64];  // [buf][k][o][f] 36.9KB

    const int tid = threadIdx.x;
    const int f   = tid & 63;
    const int bq  = tid >> 6;                 // 0..7
    const int oq  = blockIdx.x >> 6;          // 0..3
    const int h   = blockIdx.x & 63;
    const int col = h * 64 + f;

    // ---- weight slots: tid<288 = (o:8)x(k:9)x(q:4); 16 floats x 2 p-rows ----
    const bool wOK = (tid < 288);
    int wg = 0, wl = 0;
    {
        int s = wOK ? tid : 0;
        int o_ = s / 36, rm = s - 36 * o_;
        int k_ = rm >> 2, q_ = rm & 3;
        wg = ((oq * 8 + o_) * 72 + k_) * F2 + h * 64 + 16 * q_;  // +cp*18*F2, pair +9*F2
        wl = (k_ * 8 + o_) * 64 + 16 * q_;
    }

    // ---- x slots: tid<384 = (kh:3)x(b:32)x(q:4); 16 floats x 2 channels ----
    bool xOK = false;
    int xg = 0, xl = 0;
    {
        int s = (tid < 384) ? tid : 0;
        int kh_ = s >> 7, b_ = (s >> 2) & 31, q_ = s & 3;
        int gh = h - 1 + kh_;
        xOK = (tid < 384) && ((unsigned)gh < 64u);
        xg = b_ * 32768 + gh * 64 + 16 * q_;          // + c*4096 at issue
        xl = (kh_ * 32 + b_) * 68 + 16 * q_;
    }

    // x tap indices (halo cols at w'=64 (left) and 65 (right), zero forever)
    const int wi0 = (f == 0)  ? 64 : f - 1;
    const int wi2 = (f == 63) ? 65 : f + 1;

    float bz[8];
#pragma unroll
    for (int j = 0; j < 8; ++j) bz[j] = bias[(oq * 8 + j) * F2 + col];

    float acc[8][4];
#pragma unroll
    for (int j = 0; j < 8; ++j)
#pragma unroll
        for (int i = 0; i < 4; ++i) acc[j][i] = 0.f;

    float4 xr0[4], xr1[4], wr0[4], wr1[4];    // staged regs (one chunk in flight)

    auto ISSUEX = [&](int cp) {
        if (xOK) {
            const int c0 = xg + cp * 8192;
#pragma unroll
            for (int e = 0; e < 4; ++e) {
                xr0[e] = *(const float4*)(x + c0 + 4 * e);
                xr1[e] = *(const float4*)(x + c0 + 4096 + 4 * e);
            }
        }
    };
    auto ISSUEW = [&](int cp) {
        if (wOK) {
            const int g0 = wg + cp * 18 * F2;
#pragma unroll
            for (int e = 0; e < 4; ++e) {
                wr0[e] = *(const float4*)(wgt + g0 + 4 * e);
                wr1[e] = *(const float4*)(wgt + g0 + 9 * F2 + 4 * e);
            }
        }
    };
    auto WRITEX = [&]() {
        if (xOK) {
#pragma unroll
            for (int e = 0; e < 4; ++e) {
                uint4 pk;
                pk.x = pkh2f(xr0[e].x, xr1[e].x);
                pk.y = pkh2f(xr0[e].y, xr1[e].y);
                pk.z = pkh2f(xr0[e].z, xr1[e].z);
                pk.w = pkh2f(xr0[e].w, xr1[e].w);
                *(uint4*)&ldsX[xl + 4 * e] = pk;
            }
        }
    };
    auto WRITEW = [&](int buf) {
        if (wOK) {
#pragma unroll
            for (int e = 0; e < 4; ++e) {
                uint4 pk;
                pk.x = pkh2f(wr0[e].x, wr1[e].x);
                pk.y = pkh2f(wr0[e].y, wr1[e].y);
                pk.z = pkh2f(wr0[e].z, wr1[e].z);
                pk.w = pkh2f(wr0[e].w, wr1[e].w);
                *(uint4*)&ldsW[buf * 4608 + wl + 4 * e] = pk;
            }
        }
    };
    auto COMPUTE = [&](int wbuf) {
        const unsigned* wb = &ldsW[wbuf * 4608];
#pragma unroll
        for (int k = 0; k < 9; ++k) {
            const int kh = k / 3, kw = k - 3 * kh;
            const int wi = (kw == 0) ? wi0 : ((kw == 1) ? f : wi2);
            h2 wv[8];
#pragma unroll
            for (int j = 0; j < 8; ++j) wv[j] = bch2(wb[k * 512 + j * 64 + f]);
#pragma unroll
            for (int i = 0; i < 4; ++i) {
                h2 xv = bch2(ldsX[(kh * 32 + bq * 4 + i) * 68 + wi]);
#pragma unroll
                for (int j = 0; j < 8; ++j)
                    acc[j][i] = DOT2(wv[j], xv, acc[j][i]);
            }
        }
    };

    // ---- prologue: zero x LDS (halos stay zero forever); chunk0 staged ----
    ISSUEX(0); ISSUEW(0);
    for (int i = tid; i < 3 * 32 * 68; i += 512) ldsX[i] = 0u;
    __syncthreads();                       // drains ISSUE(0) (unavoidable once)
    WRITEX(); WRITEW(0);
    __syncthreads();                       // chunk0 visible; nothing in flight
    ISSUEX(1); ISSUEW(1);                  // overlaps COMPUTE(0)

#pragma unroll
    for (int cp = 0; cp < 4; ++cp) {
        COMPUTE(cp & 1);                   // prefetch (cp+1) lands during this
        if (cp < 3) {
            __syncthreads();               // x reads done; drain ~free now
            WRITEX(); WRITEW((cp + 1) & 1);
            __syncthreads();               // writes visible
            if (cp < 2) { ISSUEX(cp + 2); ISSUEW(cp + 2); }  // overlap next COMPUTE
        }
    }
    __syncthreads();                       // free ldsX for scratch reuse

    // ---- epilogue: bias, y store, BN partials ----
    float s_[8], ss_[8];
#pragma unroll
    for (int j = 0; j < 8; ++j) {
        s_[j] = 0.f; ss_[j] = 0.f;
#pragma unroll
        for (int i = 0; i < 4; ++i) {
            float a = acc[j][i] + bz[j];
            y[(size_t)((bq * 4 + i) * Oo + oq * 8 + j) * F2 + col] = (YT)a;
            s_[j] += a; ss_[j] = fmaf(a, a, ss_[j]);
        }
    }
    if (psum != nullptr) {
#pragma unroll
        for (int j = 0; j < 8; ++j)
#pragma unroll
            for (int d = 32; d >= 1; d >>= 1) {
                s_[j]  += __shfl_down(s_[j],  d, 64);
                ss_[j] += __shfl_down(ss_[j], d, 64);
            }
        float* scr = (float*)ldsX;          // [2][bq:8][o:8]
        if (f == 0) {
#pragma unroll
            for (int j = 0; j < 8; ++j) {
                scr[bq * 8 + j]      = s_[j];
                scr[64 + bq * 8 + j] = ss_[j];
            }
        }
        __syncthreads();
        if (tid < 64) {
            int j = tid >> 3, g = tid & 7;  // g = bq
            float v  = scr[g * 8 + j];
            float vv = scr[64 + g * 8 + j];
#pragma unroll
            for (int d = 4; d >= 1; d >>= 1) {
                v  += __shfl_down(v,  d, 8);
                vv += __shfl_down(vv, d, 8);
            }
            if (g == 0) {
                psum[(oq * 8 + j) * SLOTS + h]   = v;
                psumsq[(oq * 8 + j) * SLOTS + h] = vv;
            }
        }
    }
}

// ---- fused stats+apply: each block serves one o; 64 lanes reduce psum ----
__global__ __launch_bounds__(256) void bnapply_fused_kernel(
    const _Float16* __restrict__ yh, const float* __restrict__ psum,
    const float* __restrict__ psumsq, const float* __restrict__ gamma,
    const float* __restrict__ beta, float* __restrict__ y)
{
    __shared__ float scsh[2];
    const int o = (blockIdx.x >> 1) & 31;      // constant per block
    const int t = threadIdx.x;
    if (t < 64) {
        float v  = psum[o * SLOTS + t];
        float vv = psumsq[o * SLOTS + t];
#pragma unroll
        for (int d = 32; d >= 1; d >>= 1) {
            v  += __shfl_down(v,  d, 64);
            vv += __shfl_down(vv, d, 64);
        }
        if (t == 0) {
            float mean = v / (float)NTOT;
            float var  = vv / (float)NTOT - mean * mean;
            float rstd = rsqrtf(var + 1e-5f);
            float scl  = gamma[o] * rstd;
            scsh[0] = scl;
            scsh[1] = beta[o] - mean * scl;
        }
    }
    __syncthreads();
    const float scl = scsh[0], sh = scsh[1];

    int i = blockIdx.x * 256 + t;              // 8-element packs; 524288 total
    h8 v = ((const h8*)yh)[i];
    float4 lo, hi;
    lo.x = fmaf((float)v[0], scl, sh);
    lo.y = fmaf((float)v[1], scl, sh);
    lo.z = fmaf((float)v[2], scl, sh);
    lo.w = fmaf((float)v[3], scl, sh);
    hi.x = fmaf((float)v[4], scl, sh);
    hi.y = fmaf((float)v[5], scl, sh);
    hi.z = fmaf((float)v[6], scl, sh);
    hi.w = fmaf((float)v[7], scl, sh);
    ((float4*)y)[2 * i]     = lo;
    ((float4*)y)[2 * i + 1] = hi;
}

// ======== fallback kernels (r16-proven) ========
__global__ __launch_bounds__(64) void bnstats_kernel(
    const float* __restrict__ psum, const float* __restrict__ psumsq,
    const float* __restrict__ gamma, const float* __restrict__ beta,
    float* __restrict__ scsh)
{
    const int o = blockIdx.x;
    const int t = threadIdx.x;
    float s  = psum[o * SLOTS + t];
    float ss = psumsq[o * SLOTS + t];
#pragma unroll
    for (int d = 32; d >= 1; d >>= 1) {
        s  += __shfl_down(s, d, 64);
        ss += __shfl_down(ss, d, 64);
    }
    if (t == 0) {
        float mean = s / (float)NTOT;
        float var  = ss / (float)NTOT - mean * mean;
        float rstd = rsqrtf(var + 1e-5f);
        float scl  = gamma[o] * rstd;
        scsh[o]      = scl;
        scsh[Oo + o] = beta[o] - mean * scl;
    }
}

__global__ __launch_bounds__(256) void bnapply_kernel(
    float* __restrict__ y, const float* __restrict__ scsh)
{
    int i = blockIdx.x * 256 + threadIdx.x;    // float4 index
    float4 v = ((const float4*)y)[i];
    int o = (i >> 10) & 31;
    float scl = scsh[o], sh = scsh[Oo + o];
    v.x = fmaf(v.x, scl, sh);
    v.y = fmaf(v.y, scl, sh);
    v.z = fmaf(v.z, scl, sh);
    v.w = fmaf(v.w, scl, sh);
    ((float4*)y)[i] = v;
}

__global__ __launch_bounds__(256) void bnreduce_y_kernel(
    const float* __restrict__ y, float* __restrict__ seg, float* __restrict__ segsq)
{
    const int o  = blockIdx.x >> 3;
    const int sg = blockIdx.x & 7;
    const int t  = threadIdx.x;
    float s = 0.f, ss = 0.f;
    for (int i = t; i < 4 * 1024; i += 256) {
        int b   = sg * 4 + (i >> 10);
        int fof = (i & 1023) * 4;
        float4 v = *(const float4*)(y + (size_t)(b * Oo + o) * F2 + fof);
        s  += (v.x + v.y) + (v.z + v.w);
        ss += v.x * v.x + v.y * v.y + v.z * v.z + v.w * v.w;
    }
#pragma unroll
    for (int d = 32; d >= 1; d >>= 1) {
        s  += __shfl_down(s, d, 64);
        ss += __shfl_down(ss, d, 64);
    }
    __shared__ float ls[4], lss[4];
    int wv = t >> 6, ln = t & 63;
    if (ln == 0) { ls[wv] = s; lss[wv] = ss; }
    __syncthreads();
    if (t == 0) {
        seg[blockIdx.x]   = (ls[0] + ls[1]) + (ls[2] + ls[3]);
        segsq[blockIdx.x] = (lss[0] + lss[1]) + (lss[2] + lss[3]);
    }
}

__global__ __launch_bounds__(256) void bnstats2_kernel(
    const float* __restrict__ seg, const float* __restrict__ segsq,
    const float* __restrict__ gamma, const float* __restrict__ beta,
    float* __restrict__ scsh)
{
    const int t = threadIdx.x;
    const int o = t >> 3, g = t & 7;
    float v  = seg[t];
    float vv = segsq[t];
#pragma unroll
    for (int d = 4; d >= 1; d >>= 1) {
        v  += __shfl_down(v,  d, 8);
        vv += __shfl_down(vv, d, 8);
    }
    if (g == 0) {
        float mean = v / (float)NTOT;
        float var  = vv / (float)NTOT - mean * mean;
        float rstd = rsqrtf(var + 1e-5f);
        float scl  = gamma[o] * rstd;
        scsh[o]      = scl;
        scsh[Oo + o] = beta[o] - mean * scl;
    }
}

extern "C" void kernel_launch(void* const* d_in, const int* in_sizes, int n_in,
                              void* d_out, int out_size, void* d_ws, size_t ws_size,
                              hipStream_t stream)
{
    const float* x     = (const float*)d_in[0];
    const float* wgt   = (const float*)d_in[1];
    const float* bias  = (const float*)d_in[2];
    const float* gamma = (const float*)d_in[3];
    const float* beta  = (const float*)d_in[4];
    float* y = (float*)d_out;

    const size_t n_elems    = (size_t)NTOT * Oo;              // 4,194,304
    const size_t yh_bytes   = n_elems * sizeof(_Float16);     // 8 MiB
    const size_t psum_bytes = (size_t)(2 * Oo * SLOTS + 2 * Oo) * sizeof(float);

    if (ws_size >= yh_bytes + psum_bytes) {
        // primary: f16 intermediate y in ws; 2 dispatches
        _Float16* yh  = (_Float16*)d_ws;
        float* psum   = (float*)((char*)d_ws + yh_bytes);     // [Oo][SLOTS]
        float* psumsq = psum + Oo * SLOTS;
        svconv_kernel<_Float16><<<GRID, 512, 0, stream>>>(x, wgt, bias, yh, psum, psumsq);
        bnapply_fused_kernel<<<(int)(n_elems / 8 / 256), 256, 0, stream>>>(
            yh, psum, psumsq, gamma, beta, y);
    } else if (ws_size >= psum_bytes) {
        // secondary: fp32 y in d_out, partials in ws
        float* psum   = (float*)d_ws;
        float* psumsq = psum + Oo * SLOTS;
        float* scsh   = psumsq + Oo * SLOTS;
        svconv_kernel<float><<<GRID, 512, 0, stream>>>(x, wgt, bias, y, psum, psumsq);
        bnstats_kernel<<<Oo, 64, 0, stream>>>(psum, psumsq, gamma, beta, scsh);
        bnapply_kernel<<<(int)(n_elems / 4 / 256), 256, 0, stream>>>(y, scsh);
    } else {
        // tertiary: tiny scratch — reduce y directly
        float* seg   = (float*)d_ws;                          // [256]
        float* segsq = seg + 256;
        float* scsh  = segsq + 256;
        svconv_kernel<float><<<GRID, 512, 0, stream>>>(x, wgt, bias, y, nullptr, nullptr);
        bnreduce_y_kernel<<<256, 256, 0, stream>>>(y, seg, segsq);
        bnstats2_kernel<<<1, 256, 0, stream>>>(seg, segsq, gamma, beta, scsh);
        bnapply_kernel<<<(int)(n_elems / 4 / 256), 256, 0, stream>>>(y, scsh);
    }
}

// Round 22
// 30.111 us; speedup vs baseline: 1.7502x; 1.0036x over previous
//
#include <hip/hip_runtime.h>

#define Oo    32
#define F2    4096
#define GRID  512            // (oq:8) x (h:64) -> 2 blocks/CU
#define SLOTS 64             // per-o partial slots: one per h-row block
#define NTOT  (32 * F2)

typedef _Float16 h2 __attribute__((ext_vector_type(2)));
typedef _Float16 h8 __attribute__((ext_vector_type(8)));

#if __has_builtin(__builtin_amdgcn_fdot2)
#define DOT2(a, b, c) __builtin_amdgcn_fdot2((a), (b), (c), false)
#else
__device__ __forceinline__ float DOT2(h2 a, h2 b, float c) {
    return c + (float)a.x * (float)b.x + (float)a.y * (float)b.y;
}
#endif

__device__ __forceinline__ unsigned pkh2f(float a, float b) {
    h2 t; t.x = (_Float16)a; t.y = (_Float16)b;
    return __builtin_bit_cast(unsigned, t);
}
__device__ __forceinline__ h2 bch2(unsigned u) { return __builtin_bit_cast(h2, u); }

// r21 structure (full-row DRAM-contiguous tile, 2-dispatch tail; 30.2us,
// passed post-timing) at 2 BLOCKS/CU: o-split deepened 4->8 groups (4 o's
// per block, grid 512 = (oq:8)x(h:64)). Per-thread state acc[4][4] -> VGPR
// ~80; LDS 26.1(x)+18.4(w)=44.5KB -> two blocks co-resident (89KB, 16
// waves/CU). Rationale: svconv was pinned at ~24us = 4 serialized ~3.5us
// load-bound chunks + prologue with ONE block/CU — no second pipeline to
// cover barrier/drain phases. Two independent blocks interleave them.
// Weights still read exactly once chip-wide (256B-contiguous rows); x
// replication x8 is L2/L3-served (x = 4MB).
template <typename YT>
__global__ __launch_bounds__(512) void svconv_kernel(
    const float* __restrict__ x, const float* __restrict__ wgt,
    const float* __restrict__ bias, YT* __restrict__ y,
    float* __restrict__ psum, float* __restrict__ psumsq)
{
    __shared__ __align__(16) unsigned ldsX[3 * 32 * 68];     // [kh][b][w'] 26.1KB
    __shared__ __align__(16) unsigned ldsW[2 * 9 * 4 * 64];  // [buf][k][o][f] 18.4KB

    const int tid = threadIdx.x;
    const int f   = tid & 63;
    const int bq  = tid >> 6;                 // 0..7
    const int oq  = blockIdx.x >> 6;          // 0..7
    const int h   = blockIdx.x & 63;
    const int col = h * 64 + f;

    // ---- weight slots: tid<144 = (o:4)x(k:9)x(q:4); 16 floats x 2 p-rows ----
    const bool wOK = (tid < 144);
    int wg = 0, wl = 0;
    {
        int s = wOK ? tid : 0;
        int o_ = s / 36, rm = s - 36 * o_;
        int k_ = rm >> 2, q_ = rm & 3;
        wg = ((oq * 4 + o_) * 72 + k_) * F2 + h * 64 + 16 * q_;  // +cp*18*F2, pair +9*F2
        wl = (k_ * 4 + o_) * 64 + 16 * q_;
    }

    // ---- x slots: tid<384 = (kh:3)x(b:32)x(q:4); 16 floats x 2 channels ----
    bool xOK = false;
    int xg = 0, xl = 0;
    {
        int s = (tid < 384) ? tid : 0;
        int kh_ = s >> 7, b_ = (s >> 2) & 31, q_ = s & 3;
        int gh = h - 1 + kh_;
        xOK = (tid < 384) && ((unsigned)gh < 64u);
        xg = b_ * 32768 + gh * 64 + 16 * q_;          // + c*4096 at issue
        xl = (kh_ * 32 + b_) * 68 + 16 * q_;
    }

    // x tap indices (halo cols at w'=64 (left) and 65 (right), zero forever)
    const int wi0 = (f == 0)  ? 64 : f - 1;
    const int wi2 = (f == 63) ? 65 : f + 1;

    float bz[4];
#pragma unroll
    for (int j = 0; j < 4; ++j) bz[j] = bias[(oq * 4 + j) * F2 + col];

    float acc[4][4];
#pragma unroll
    for (int j = 0; j < 4; ++j)
#pragma unroll
        for (int i = 0; i < 4; ++i) acc[j][i] = 0.f;

    float4 xr0[4], xr1[4], wr0[4], wr1[4];    // staged regs (one chunk in flight)

    auto ISSUEX = [&](int cp) {
        if (xOK) {
            const int c0 = xg + cp * 8192;
#pragma unroll
            for (int e = 0; e < 4; ++e) {
                xr0[e] = *(const float4*)(x + c0 + 4 * e);
                xr1[e] = *(const float4*)(x + c0 + 4096 + 4 * e);
            }
        }
    };
    auto ISSUEW = [&](int cp) {
        if (wOK) {
            const int g0 = wg + cp * 18 * F2;
#pragma unroll
            for (int e = 0; e < 4; ++e) {
                wr0[e] = *(const float4*)(wgt + g0 + 4 * e);
                wr1[e] = *(const float4*)(wgt + g0 + 9 * F2 + 4 * e);
            }
        }
    };
    auto WRITEX = [&]() {
        if (xOK) {
#pragma unroll
            for (int e = 0; e < 4; ++e) {
                uint4 pk;
                pk.x = pkh2f(xr0[e].x, xr1[e].x);
                pk.y = pkh2f(xr0[e].y, xr1[e].y);
                pk.z = pkh2f(xr0[e].z, xr1[e].z);
                pk.w = pkh2f(xr0[e].w, xr1[e].w);
                *(uint4*)&ldsX[xl + 4 * e] = pk;
            }
        }
    };
    auto WRITEW = [&](int buf) {
        if (wOK) {
#pragma unroll
            for (int e = 0; e < 4; ++e) {
                uint4 pk;
                pk.x = pkh2f(wr0[e].x, wr1[e].x);
                pk.y = pkh2f(wr0[e].y, wr1[e].y);
                pk.z = pkh2f(wr0[e].z, wr1[e].z);
                pk.w = pkh2f(wr0[e].w, wr1[e].w);
                *(uint4*)&ldsW[buf * 2304 + wl + 4 * e] = pk;
            }
        }
    };
    auto COMPUTE = [&](int wbuf) {
        const unsigned* wb = &ldsW[wbuf * 2304];
#pragma unroll
        for (int k = 0; k < 9; ++k) {
            const int kh = k / 3, kw = k - 3 * kh;
            const int wi = (kw == 0) ? wi0 : ((kw == 1) ? f : wi2);
            h2 wv[4];
#pragma unroll
            for (int j = 0; j < 4; ++j) wv[j] = bch2(wb[k * 256 + j * 64 + f]);
#pragma unroll
            for (int i = 0; i < 4; ++i) {
                h2 xv = bch2(ldsX[(kh * 32 + bq * 4 + i) * 68 + wi]);
#pragma unroll
                for (int j = 0; j < 4; ++j)
                    acc[j][i] = DOT2(wv[j], xv, acc[j][i]);
            }
        }
    };

    // ---- prologue: zero x LDS (halos stay zero forever); chunk0 staged ----
    ISSUEX(0); ISSUEW(0);
    for (int i = tid; i < 3 * 32 * 68; i += 512) ldsX[i] = 0u;
    __syncthreads();                       // drains ISSUE(0) (unavoidable once)
    WRITEX(); WRITEW(0);
    __syncthreads();                       // chunk0 visible; nothing in flight
    ISSUEX(1); ISSUEW(1);                  // overlaps COMPUTE(0)

#pragma unroll
    for (int cp = 0; cp < 4; ++cp) {
        COMPUTE(cp & 1);                   // prefetch (cp+1) lands during this
        if (cp < 3) {
            __syncthreads();               // x reads done
            WRITEX(); WRITEW((cp + 1) & 1);
            __syncthreads();               // writes visible
            if (cp < 2) { ISSUEX(cp + 2); ISSUEW(cp + 2); }  // overlap next COMPUTE
        }
    }
    __syncthreads();                       // free ldsX for scratch reuse

    // ---- epilogue: bias, y store, BN partials ----
    float s_[4], ss_[4];
#pragma unroll
    for (int j = 0; j < 4; ++j) {
        s_[j] = 0.f; ss_[j] = 0.f;
#pragma unroll
        for (int i = 0; i < 4; ++i) {
            float a = acc[j][i] + bz[j];
            y[(size_t)((bq * 4 + i) * Oo + oq * 4 + j) * F2 + col] = (YT)a;
            s_[j] += a; ss_[j] = fmaf(a, a, ss_[j]);
        }
    }
    if (psum != nullptr) {
#pragma unroll
        for (int j = 0; j < 4; ++j)
#pragma unroll
            for (int d = 32; d >= 1; d >>= 1) {
                s_[j]  += __shfl_down(s_[j],  d, 64);
                ss_[j] += __shfl_down(ss_[j], d, 64);
            }
        float* scr = (float*)ldsX;          // [2][bq:8][o:4]
        if (f == 0) {
#pragma unroll
            for (int j = 0; j < 4; ++j) {
                scr[bq * 4 + j]      = s_[j];
                scr[32 + bq * 4 + j] = ss_[j];
            }
        }
        __syncthreads();
        if (tid < 32) {
            int j = tid >> 3, g = tid & 7;  // j = o-local (0..3), g = bq
            float v  = scr[g * 4 + j];
            float vv = scr[32 + g * 4 + j];
#pragma unroll
            for (int d = 4; d >= 1; d >>= 1) {
                v  += __shfl_down(v,  d, 8);
                vv += __shfl_down(vv, d, 8);
            }
            if (g == 0) {
                psum[(oq * 4 + j) * SLOTS + h]   = v;
                psumsq[(oq * 4 + j) * SLOTS + h] = vv;
            }
        }
    }
}

// ---- fused stats+apply: each block serves one o; 64 lanes reduce psum ----
__global__ __launch_bounds__(256) void bnapply_fused_kernel(
    const _Float16* __restrict__ yh, const float* __restrict__ psum,
    const float* __restrict__ psumsq, const float* __restrict__ gamma,
    const float* __restrict__ beta, float* __restrict__ y)
{
    __shared__ float scsh[2];
    const int o = (blockIdx.x >> 1) & 31;      // constant per block
    const int t = threadIdx.x;
    if (t < 64) {
        float v  = psum[o * SLOTS + t];
        float vv = psumsq[o * SLOTS + t];
#pragma unroll
        for (int d = 32; d >= 1; d >>= 1) {
            v  += __shfl_down(v,  d, 64);
            vv += __shfl_down(vv, d, 64);
        }
        if (t == 0) {
            float mean = v / (float)NTOT;
            float var  = vv / (float)NTOT - mean * mean;
            float rstd = rsqrtf(var + 1e-5f);
            float scl  = gamma[o] * rstd;
            scsh[0] = scl;
            scsh[1] = beta[o] - mean * scl;
        }
    }
    __syncthreads();
    const float scl = scsh[0], sh = scsh[1];

    int i = blockIdx.x * 256 + t;              // 8-element packs; 524288 total
    h8 v = ((const h8*)yh)[i];
    float4 lo, hi;
    lo.x = fmaf((float)v[0], scl, sh);
    lo.y = fmaf((float)v[1], scl, sh);
    lo.z = fmaf((float)v[2], scl, sh);
    lo.w = fmaf((float)v[3], scl, sh);
    hi.x = fmaf((float)v[4], scl, sh);
    hi.y = fmaf((float)v[5], scl, sh);
    hi.z = fmaf((float)v[6], scl, sh);
    hi.w = fmaf((float)v[7], scl, sh);
    ((float4*)y)[2 * i]     = lo;
    ((float4*)y)[2 * i + 1] = hi;
}

// ======== fallback kernels ========
__global__ __launch_bounds__(64) void bnstats_kernel(
    const float* __restrict__ psum, const float* __restrict__ psumsq,
    const float* __restrict__ gamma, const float* __restrict__ beta,
    float* __restrict__ scsh)
{
    const int o = blockIdx.x;
    const int t = threadIdx.x;
    float s  = psum[o * SLOTS + t];
    float ss = psumsq[o * SLOTS + t];
#pragma unroll
    for (int d = 32; d >= 1; d >>= 1) {
        s  += __shfl_down(s, d, 64);
        ss += __shfl_down(ss, d, 64);
    }
    if (t == 0) {
        float mean = s / (float)NTOT;
        float var  = ss / (float)NTOT - mean * mean;
        float rstd = rsqrtf(var + 1e-5f);
        float scl  = gamma[o] * rstd;
        scsh[o]      = scl;
        scsh[Oo + o] = beta[o] - mean * scl;
    }
}

__global__ __launch_bounds__(256) void bnapply_kernel(
    float* __restrict__ y, const float* __restrict__ scsh)
{
    int i = blockIdx.x * 256 + threadIdx.x;    // float4 index
    float4 v = ((const float4*)y)[i];
    int o = (i >> 10) & 31;
    float scl = scsh[o], sh = scsh[Oo + o];
    v.x = fmaf(v.x, scl, sh);
    v.y = fmaf(v.y, scl, sh);
    v.z = fmaf(v.z, scl, sh);
    v.w = fmaf(v.w, scl, sh);
    ((float4*)y)[i] = v;
}

__global__ __launch_bounds__(256) void bnreduce_y_kernel(
    const float* __restrict__ y, float* __restrict__ seg, float* __restrict__ segsq)
{
    const int o  = blockIdx.x >> 3;
    const int sg = blockIdx.x & 7;
    const int t  = threadIdx.x;
    float s = 0.f, ss = 0.f;
    for (int i = t; i < 4 * 1024; i += 256) {
        int b   = sg * 4 + (i >> 10);
        int fof = (i & 1023) * 4;
        float4 v = *(const float4*)(y + (size_t)(b * Oo + o) * F2 + fof);
        s  += (v.x + v.y) + (v.z + v.w);
        ss += v.x * v.x + v.y * v.y + v.z * v.z + v.w * v.w;
    }
#pragma unroll
    for (int d = 32; d >= 1; d >>= 1) {
        s  += __shfl_down(s, d, 64);
        ss += __shfl_down(ss, d, 64);
    }
    __shared__ float ls[4], lss[4];
    int wv = t >> 6, ln = t & 63;
    if (ln == 0) { ls[wv] = s; lss[wv] = ss; }
    __syncthreads();
    if (t == 0) {
        seg[blockIdx.x]   = (ls[0] + ls[1]) + (ls[2] + ls[3]);
        segsq[blockIdx.x] = (lss[0] + lss[1]) + (lss[2] + lss[3]);
    }
}

__global__ __launch_bounds__(256) void bnstats2_kernel(
    const float* __restrict__ seg, const float* __restrict__ segsq,
    const float* __restrict__ gamma, const float* __restrict__ beta,
    float* __restrict__ scsh)
{
    const int t = threadIdx.x;
    const int o = t >> 3, g = t & 7;
    float v  = seg[t];
    float vv = segsq[t];
#pragma unroll
    for (int d = 4; d >= 1; d >>= 1) {
        v  += __shfl_down(v,  d, 8);
        vv += __shfl_down(vv, d, 8);
    }
    if (g == 0) {
        float mean = v / (float)NTOT;
        float var  = vv / (float)NTOT - mean * mean;
        float rstd = rsqrtf(var + 1e-5f);
        float scl  = gamma[o] * rstd;
        scsh[o]      = scl;
        scsh[Oo + o] = beta[o] - mean * scl;
    }
}

extern "C" void kernel_launch(void* const* d_in, const int* in_sizes, int n_in,
                              void* d_out, int out_size, void* d_ws, size_t ws_size,
                              hipStream_t stream)
{
    const float* x     = (const float*)d_in[0];
    const float* wgt   = (const float*)d_in[1];
    const float* bias  = (const float*)d_in[2];
    const float* gamma = (const float*)d_in[3];
    const float* beta  = (const float*)d_in[4];
    float* y = (float*)d_out;

    const size_t n_elems    = (size_t)NTOT * Oo;              // 4,194,304
    const size_t yh_bytes   = n_elems * sizeof(_Float16);     // 8 MiB
    const size_t psum_bytes = (size_t)(2 * Oo * SLOTS + 2 * Oo) * sizeof(float);

    if (ws_size >= yh_bytes + psum_bytes) {
        // primary: f16 intermediate y in ws; 2 dispatches
        _Float16* yh  = (_Float16*)d_ws;
        float* psum   = (float*)((char*)d_ws + yh_bytes);     // [Oo][SLOTS]
        float* psumsq = psum + Oo * SLOTS;
        svconv_kernel<_Float16><<<GRID, 512, 0, stream>>>(x, wgt, bias, yh, psum, psumsq);
        bnapply_fused_kernel<<<(int)(n_elems / 8 / 256), 256, 0, stream>>>(
            yh, psum, psumsq, gamma, beta, y);
    } else if (ws_size >= psum_bytes) {
        // secondary: fp32 y in d_out, partials in ws
        float* psum   = (float*)d_ws;
        float* psumsq = psum + Oo * SLOTS;
        float* scsh   = psumsq + Oo * SLOTS;
        svconv_kernel<float><<<GRID, 512, 0, stream>>>(x, wgt, bias, y, psum, psumsq);
        bnstats_kernel<<<Oo, 64, 0, stream>>>(psum, psumsq, gamma, beta, scsh);
        bnapply_kernel<<<(int)(n_elems / 4 / 256), 256, 0, stream>>>(y, scsh);
    } else {
        // tertiary: tiny scratch — reduce y directly
        float* seg   = (float*)d_ws;                          // [256]
        float* segsq = seg + 256;
        float* scsh  = segsq + 256;
        svconv_kernel<float><<<GRID, 512, 0, stream>>>(x, wgt, bias, y, nullptr, nullptr);
        bnreduce_y_kernel<<<256, 256, 0, stream>>>(y, seg, segsq);
        bnstats2_kernel<<<1, 256, 0, stream>>>(seg, segsq, gamma, beta, scsh);
        bnapply_kernel<<<(int)(n_elems / 4 / 256), 256, 0, stream>>>(y, scsh);
    }
}